// Round 13
// baseline (905.314 us; speedup 1.0000x reference)
//
#include <hip/hip_runtime.h>

// LSTMFeatureExtractor: 2-layer LSTM (H=128) over B=512, T=512, + a*relu(a) head.
// Round 13 = round-12 pipeline, balanced. 96 blocks x 512 thr, 3 roles:
//  P0: seeds0 = bias0 + x@Wih0^T -> 4-deep f16 ring (per-consumer-thread order).
//  S0: layer-0 recurrence (16 hh-MFMAs from seeds0) AND layer-1 input projection:
//      at step u it has hf = h0(u-1) loaded as B-frag anyway -> 4 extra MFMAs
//      (bias1 + Wih1*hf) emit seeds1(u-1) into a second 4-deep f16 ring.
//  S1: layer-1 recurrence + head, LIGHT: seeds1 from ring (no ih MFMAs, no
//      staging, no xbuf), 16 hh + 4 head MFMAs, a*relu(a) accumulation -> out.
// Flags: fg0 P0->S0 ready, fs0 S0->P0 credit, fg1 S0->S1 ready (slot c complete
// at S0 step c*8+8, i.e. s=0 of chunk c+1; epilogue completes slot 63),
// fs1 S1->S0 credit (depth 4). Deadlock-audited; 96 blocks co-resident.

typedef _Float16 half8  __attribute__((ext_vector_type(8)));
typedef _Float16 half4_ __attribute__((ext_vector_type(4)));
typedef float    f32x4  __attribute__((ext_vector_type(4)));

#define H_    128
#define T_    512
#define B_    512
#define BCH   16
#define NBG   32
#define NCH   64                  // 8-step chunks
#define KPAD  136
#define RS    4                   // ring depths (seeds0, seeds1)
#define SEEDSLOT (8 * 4 * 512 * 4)    // halves per (bg,slot): 65536 (128KB)

#define LOG2E 1.44269504089f

__device__ __forceinline__ float sigm_(float x) {
    return __builtin_amdgcn_rcpf(1.f + __builtin_amdgcn_exp2f(-LOG2E * x));
}
__device__ __forceinline__ float tanh_(float x) {
    return 1.f - 2.f * __builtin_amdgcn_rcpf(1.f + __builtin_amdgcn_exp2f((2.f * LOG2E) * x));
}
__device__ __forceinline__ void lds_barrier() {
    __builtin_amdgcn_sched_barrier(0);
    asm volatile("s_waitcnt lgkmcnt(0)" ::: "memory");
    __builtin_amdgcn_sched_barrier(0);
    __builtin_amdgcn_s_barrier();
    __builtin_amdgcn_sched_barrier(0);
}
__device__ __forceinline__ void fwait(const int* p, int tgt) {
    while (__hip_atomic_load(p, __ATOMIC_ACQUIRE, __HIP_MEMORY_SCOPE_AGENT) < tgt)
        __builtin_amdgcn_s_sleep(2);
}
__device__ __forceinline__ void frel(int* p, int v) {
    __hip_atomic_store(p, v, __ATOMIC_RELEASE, __HIP_MEMORY_SCOPE_AGENT);
}
__device__ __forceinline__ f32x4 cvt4(half4_ h) {
    return f32x4{(float)h[0], (float)h[1], (float)h[2], (float)h[3]};
}
__device__ __forceinline__ half4_ cvh4(f32x4 v) {
    return half4_{(_Float16)v[0], (_Float16)v[1], (_Float16)v[2], (_Float16)v[3]};
}

#define MFMA16(A, Bv, C) __builtin_amdgcn_mfma_f32_16x16x32_f16((A), (Bv), (C), 0, 0, 0)

__global__ void __launch_bounds__(512)
lstm3(const float* __restrict__ y,
      const float* __restrict__ Wih0, const float* __restrict__ Whh0,
      const float* __restrict__ bih0, const float* __restrict__ bhh0,
      const float* __restrict__ Wih1, const float* __restrict__ Whh1,
      const float* __restrict__ bih1, const float* __restrict__ bhh1,
      const float* __restrict__ Wa,  const float* __restrict__ ba,
      _Float16* __restrict__ seeds0, _Float16* __restrict__ seeds1,
      int* __restrict__ flags, float* __restrict__ out)
{
    __shared__ _Float16 xbuf[8][16][KPAD];   // P0 only
    __shared__ _Float16 hbuf[2][16][KPAD];   // S0/S1 h state

    const int tid = threadIdx.x;
    const int w   = tid >> 6;
    const int l   = tid & 63;
    const int g   = l >> 4;
    const int cl  = l & 15;
    const int role = blockIdx.x % 3;     // 0=P0 1=S0 2=S1
    const int bg   = blockIdx.x / 3;
    const int b0   = bg * BCH;

    int* fg0 = flags;        // P0 -> S0
    int* fs0 = flags + 32;   // S0 -> P0 credit
    int* fg1 = flags + 64;   // S0 -> S1
    int* fs1 = flags + 96;   // S1 -> S0 credit

    { // zero hbuf (initial h state)
        int* q = (int*)&hbuf[0][0][0];
        for (int i = tid; i < (int)(sizeof(hbuf) / 4); i += 512) q[i] = 0;
    }

    if (role == 0) {
        // ====================== P0: layer-0 input projection ======================
        half8 wf[4][4];
        #pragma unroll
        for (int gt = 0; gt < 4; ++gt) {
            const int grow = gt * 128 + w * 16 + cl;
            #pragma unroll
            for (int kt = 0; kt < 4; ++kt) {
                const float* pa = Wih0 + grow * H_ + kt * 32 + g * 8;
                f32x4 a0 = *(const f32x4*)(pa);
                f32x4 a1 = *(const f32x4*)(pa + 4);
                half8 fa;
                #pragma unroll
                for (int e = 0; e < 4; ++e) { fa[e] = (_Float16)a0[e]; fa[e + 4] = (_Float16)a1[e]; }
                wf[gt][kt] = fa;
            }
        }
        f32x4 bias[4];
        #pragma unroll
        for (int gt = 0; gt < 4; ++gt)
            #pragma unroll
            for (int r = 0; r < 4; ++r) {
                const int R = gt * 128 + w * 16 + g * 4 + r;
                bias[gt][r] = bih0[R] + bhh0[R];
            }
        __syncthreads();

        for (int c = 0; c < NCH; ++c) {
            if (tid == 0 && c >= RS) fwait(&fs0[bg], c - (RS - 1));
            __syncthreads();

            #pragma unroll
            for (int rr = 0; rr < 4; ++rr) {
                const int q = tid + rr * 512;
                const int b = q >> 7, k = q & 127;
                const float* src = y + ((size_t)((b0 + b) * H_ + k)) * T_ + c * 8;
                f32x4 v0 = *(const f32x4*)(src);
                f32x4 v1 = *(const f32x4*)(src + 4);
                #pragma unroll
                for (int e = 0; e < 4; ++e) {
                    xbuf[e][b][k]     = (_Float16)v0[e];
                    xbuf[e + 4][b][k] = (_Float16)v1[e];
                }
            }
            lds_barrier();

            _Float16* sb = seeds0 + (size_t)(bg * RS + (c & (RS - 1))) * SEEDSLOT;
            for (int s = 0; s < 8; ++s) {
                half8 xf[4];
                #pragma unroll
                for (int kt = 0; kt < 4; ++kt)
                    xf[kt] = *(const half8*)&xbuf[s][cl][kt * 32 + g * 8];
                #pragma unroll
                for (int gt = 0; gt < 4; ++gt) {
                    f32x4 acc = bias[gt];
                    #pragma unroll
                    for (int kt = 0; kt < 4; ++kt)
                        acc = MFMA16(wf[gt][kt], xf[kt], acc);
                    *(half4_*)(sb + ((size_t)(s * 4 + gt) * 512 + tid) * 4) = cvh4(acc);
                }
            }
            __syncthreads();                 // drain seed stores
            if (tid == 0) frel(&fg0[bg], c + 1);
        }
    } else if (role == 1) {
        // ============ S0: layer-0 recurrence + layer-1 projection ============
        half8 whh[4][4], wih1f[4][4];
        #pragma unroll
        for (int gt = 0; gt < 4; ++gt) {
            const int grow = gt * 128 + w * 16 + cl;
            #pragma unroll
            for (int kt = 0; kt < 4; ++kt) {
                const float* pb = Whh0 + grow * H_ + kt * 32 + g * 8;
                const float* pa = Wih1 + grow * H_ + kt * 32 + g * 8;
                f32x4 c0 = *(const f32x4*)(pb);
                f32x4 c1 = *(const f32x4*)(pb + 4);
                f32x4 a0 = *(const f32x4*)(pa);
                f32x4 a1 = *(const f32x4*)(pa + 4);
                half8 fb, fa;
                #pragma unroll
                for (int e = 0; e < 4; ++e) {
                    fb[e] = (_Float16)c0[e]; fb[e + 4] = (_Float16)c1[e];
                    fa[e] = (_Float16)a0[e]; fa[e + 4] = (_Float16)a1[e];
                }
                whh[gt][kt] = fb; wih1f[gt][kt] = fa;
            }
        }
        f32x4 b1c[4];
        #pragma unroll
        for (int gt = 0; gt < 4; ++gt)
            #pragma unroll
            for (int r = 0; r < 4; ++r) {
                const int R = gt * 128 + w * 16 + g * 4 + r;
                b1c[gt][r] = bih1[R] + bhh1[R];
            }
        float cst[4] = {0.f, 0.f, 0.f, 0.f};
        __syncthreads();

        for (int c = 0; c < NCH; ++c) {
            if (tid == 0) {
                fwait(&fg0[bg], c + 1);                       // seeds0 ready
                if (c >= RS) fwait(&fs1[bg], c - (RS - 1));   // seeds1 slot free
            }
            __syncthreads();

            const _Float16* sb = seeds0 + (size_t)(bg * RS + (c & (RS - 1))) * SEEDSLOT
                               + (size_t)tid * 4;
            _Float16* s1cur = seeds1 + (size_t)(bg * RS + (c & (RS - 1))) * SEEDSLOT;
            _Float16* s1prv = seeds1 + (size_t)(bg * RS + ((c - 1) & (RS - 1))) * SEEDSLOT;

            half4_ sd[2][4];
            #pragma unroll
            for (int gt = 0; gt < 4; ++gt)
                sd[0][gt] = *(const half4_*)(sb + (size_t)(0 * 4 + gt) * 2048);
            #pragma unroll
            for (int gt = 0; gt < 4; ++gt)
                sd[1][gt] = *(const half4_*)(sb + (size_t)(1 * 4 + gt) * 2048);

            #pragma unroll
            for (int s = 0; s < 8; ++s) {
                const int rd = (s ^ 1) & 1;
                const int wr = s & 1;

                half8 hf[4];       // h0(u-1) as B-frag
                #pragma unroll
                for (int kt = 0; kt < 4; ++kt)
                    hf[kt] = *(const half8*)&hbuf[rd][cl][kt * 32 + g * 8];

                // ---- layer-1 projection of h0(u-1) -> seeds1 ----
                if (s > 0 || c > 0) {
                    _Float16* dstb = (s > 0) ? s1cur : s1prv;
                    const int pos = (s > 0) ? (s - 1) : 7;
                    #pragma unroll
                    for (int gt = 0; gt < 4; ++gt) {
                        f32x4 p = b1c[gt];
                        #pragma unroll
                        for (int kt = 0; kt < 4; ++kt)
                            p = MFMA16(wih1f[gt][kt], hf[kt], p);
                        *(half4_*)(dstb + ((size_t)(pos * 4 + gt) * 512 + tid) * 4) = cvh4(p);
                    }
                }

                // ---- layer-0 recurrence ----
                f32x4 a0 = cvt4(sd[s & 1][0]);
                f32x4 a1 = cvt4(sd[s & 1][1]);
                f32x4 a2 = cvt4(sd[s & 1][2]);
                f32x4 a3 = cvt4(sd[s & 1][3]);
                if (s + 2 < 8) {
                    #pragma unroll
                    for (int gt = 0; gt < 4; ++gt)
                        sd[s & 1][gt] =
                            *(const half4_*)(sb + (size_t)((s + 2) * 4 + gt) * 2048);
                }
                #pragma unroll
                for (int kt = 0; kt < 4; ++kt) {
                    a0 = MFMA16(whh[0][kt], hf[kt], a0);
                    a1 = MFMA16(whh[1][kt], hf[kt], a1);
                    a2 = MFMA16(whh[2][kt], hf[kt], a2);
                    a3 = MFMA16(whh[3][kt], hf[kt], a3);
                }

                half4_ h4;
                #pragma unroll
                for (int r = 0; r < 4; ++r) {
                    const float is  = sigm_(a0[r]);
                    const float fs  = sigm_(a1[r]);
                    const float gt_ = tanh_(a2[r]);
                    const float os  = sigm_(a3[r]);
                    cst[r] = fs * cst[r] + is * gt_;
                    h4[r] = (_Float16)(os * tanh_(cst[r]));
                }
                const int u0 = w * 16 + g * 4;
                *(half4_*)&hbuf[wr][cl][u0] = h4;

                if (s == 0) {
                    __syncthreads();                   // drain slot c-1 tail store
                    if (tid == 0 && c > 0) frel(&fg1[bg], c);   // slot c-1 complete
                } else if (s < 7) {
                    lds_barrier();
                } else {
                    __syncthreads();                   // seeds0 reads retired
                    if (tid == 0) frel(&fs0[bg], c + 1);
                }
            }
        }

        // epilogue: proj of h0(511) (in hbuf[1]) -> slot 63 pos 7, then fg1=64
        {
            half8 hf[4];
            #pragma unroll
            for (int kt = 0; kt < 4; ++kt)
                hf[kt] = *(const half8*)&hbuf[1][cl][kt * 32 + g * 8];
            _Float16* dstb = seeds1 + (size_t)(bg * RS + ((NCH - 1) & (RS - 1))) * SEEDSLOT;
            #pragma unroll
            for (int gt = 0; gt < 4; ++gt) {
                f32x4 p = b1c[gt];
                #pragma unroll
                for (int kt = 0; kt < 4; ++kt)
                    p = MFMA16(wih1f[gt][kt], hf[kt], p);
                *(half4_*)(dstb + ((size_t)(7 * 4 + gt) * 512 + tid) * 4) = cvh4(p);
            }
            __syncthreads();
            if (tid == 0) frel(&fg1[bg], NCH);
        }
    } else {
        // ============ S1: layer-1 recurrence + head (light) ============
        half8 whh[4][4];
        #pragma unroll
        for (int gt = 0; gt < 4; ++gt) {
            const int grow = gt * 128 + w * 16 + cl;
            #pragma unroll
            for (int kt = 0; kt < 4; ++kt) {
                const float* pb = Whh1 + grow * H_ + kt * 32 + g * 8;
                f32x4 c0 = *(const f32x4*)(pb);
                f32x4 c1 = *(const f32x4*)(pb + 4);
                half8 fb;
                #pragma unroll
                for (int e = 0; e < 4; ++e) { fb[e] = (_Float16)c0[e]; fb[e + 4] = (_Float16)c1[e]; }
                whh[gt][kt] = fb;
            }
        }
        half8 waf[4];
        f32x4 ba4  = {0.f, 0.f, 0.f, 0.f};
        f32x4 oacc = {0.f, 0.f, 0.f, 0.f};
        #pragma unroll
        for (int kt = 0; kt < 4; ++kt) {
            const float* p = Wa + (w * 16 + cl) * H_ + kt * 32 + g * 8;
            f32x4 a0 = *(const f32x4*)(p);
            f32x4 a1 = *(const f32x4*)(p + 4);
            half8 f;
            #pragma unroll
            for (int e = 0; e < 4; ++e) { f[e] = (_Float16)a0[e]; f[e + 4] = (_Float16)a1[e]; }
            waf[kt] = f;
        }
        #pragma unroll
        for (int r = 0; r < 4; ++r) ba4[r] = ba[w * 16 + g * 4 + r];

        float cst[4] = {0.f, 0.f, 0.f, 0.f};
        __syncthreads();

        for (int c = 0; c < NCH; ++c) {
            if (tid == 0) fwait(&fg1[bg], c + 1);
            __syncthreads();

            const _Float16* sb = seeds1 + (size_t)(bg * RS + (c & (RS - 1))) * SEEDSLOT
                               + (size_t)tid * 4;
            half4_ sd[2][4];
            #pragma unroll
            for (int gt = 0; gt < 4; ++gt)
                sd[0][gt] = *(const half4_*)(sb + (size_t)(0 * 4 + gt) * 2048);
            #pragma unroll
            for (int gt = 0; gt < 4; ++gt)
                sd[1][gt] = *(const half4_*)(sb + (size_t)(1 * 4 + gt) * 2048);

            #pragma unroll
            for (int s = 0; s < 8; ++s) {
                const int t  = c * 8 + s;
                const int rd = (s ^ 1) & 1;
                const int wr = s & 1;

                half8 hf[4];       // h1(t-1)
                #pragma unroll
                for (int kt = 0; kt < 4; ++kt)
                    hf[kt] = *(const half8*)&hbuf[rd][cl][kt * 32 + g * 8];

                f32x4 a0 = cvt4(sd[s & 1][0]);
                f32x4 a1 = cvt4(sd[s & 1][1]);
                f32x4 a2 = cvt4(sd[s & 1][2]);
                f32x4 a3 = cvt4(sd[s & 1][3]);
                if (s + 2 < 8) {
                    #pragma unroll
                    for (int gt = 0; gt < 4; ++gt)
                        sd[s & 1][gt] =
                            *(const half4_*)(sb + (size_t)((s + 2) * 4 + gt) * 2048);
                }
                #pragma unroll
                for (int kt = 0; kt < 4; ++kt) {
                    a0 = MFMA16(whh[0][kt], hf[kt], a0);
                    a1 = MFMA16(whh[1][kt], hf[kt], a1);
                    a2 = MFMA16(whh[2][kt], hf[kt], a2);
                    a3 = MFMA16(whh[3][kt], hf[kt], a3);
                }

                if (t > 0) {     // head term for h1(t-1)
                    f32x4 aacc = ba4;
                    #pragma unroll
                    for (int kt = 0; kt < 4; ++kt) aacc = MFMA16(waf[kt], hf[kt], aacc);
                    #pragma unroll
                    for (int r = 0; r < 4; ++r) {
                        const float a = aacc[r];
                        oacc[r] += a * fmaxf(a, 0.f);
                    }
                }

                half4_ h4;
                #pragma unroll
                for (int r = 0; r < 4; ++r) {
                    const float is  = sigm_(a0[r]);
                    const float fs  = sigm_(a1[r]);
                    const float gt_ = tanh_(a2[r]);
                    const float os  = sigm_(a3[r]);
                    cst[r] = fs * cst[r] + is * gt_;
                    h4[r] = (_Float16)(os * tanh_(cst[r]));
                }
                const int u0 = w * 16 + g * 4;
                *(half4_*)&hbuf[wr][cl][u0] = h4;

                if (s < 7) {
                    lds_barrier();
                } else {
                    __syncthreads();               // seeds1 reads retired
                    if (tid == 0) frel(&fs1[bg], c + 1);
                }
            }
        }

        // final head term for h1(T-1) in hbuf[1]
        f32x4 aacc = ba4;
        #pragma unroll
        for (int kt = 0; kt < 4; ++kt) {
            const half8 hfv = *(const half8*)&hbuf[1][cl][kt * 32 + g * 8];
            aacc = MFMA16(waf[kt], hfv, aacc);
        }
        #pragma unroll
        for (int r = 0; r < 4; ++r) {
            const float a = aacc[r];
            oacc[r] += a * fmaxf(a, 0.f);
        }
        *(f32x4*)&out[(size_t)(b0 + cl) * H_ + w * 16 + g * 4] = oacc;
    }
}

extern "C" void kernel_launch(void* const* d_in, const int* in_sizes, int n_in,
                              void* d_out, int out_size, void* d_ws, size_t ws_size,
                              hipStream_t stream) {
    const float* y    = (const float*)d_in[0];
    const float* Wih0 = (const float*)d_in[1];
    const float* Whh0 = (const float*)d_in[2];
    const float* bih0 = (const float*)d_in[3];
    const float* bhh0 = (const float*)d_in[4];
    const float* Wih1 = (const float*)d_in[5];
    const float* Whh1 = (const float*)d_in[6];
    const float* bih1 = (const float*)d_in[7];
    const float* bhh1 = (const float*)d_in[8];
    const float* Wa   = (const float*)d_in[9];
    const float* ba   = (const float*)d_in[10];
    float* out = (float*)d_out;

    const size_t SEED_BYTES = (size_t)NBG * RS * SEEDSLOT * 2;   // 16 MiB each
    char* p = (char*)d_ws;
    _Float16* seeds0 = (_Float16*)p;            p += SEED_BYTES;
    _Float16* seeds1 = (_Float16*)p;            p += SEED_BYTES;
    int*      flags  = (int*)p;

    hipMemsetAsync(flags, 0, 512, stream);
    lstm3<<<3 * NBG, 512, 0, stream>>>(y, Wih0, Whh0, bih0, bhh0,
                                       Wih1, Whh1, bih1, bhh1, Wa, ba,
                                       seeds0, seeds1, flags, out);
}